// Round 9
// baseline (603.467 us; speedup 1.0000x reference)
//
#include <hip/hip_runtime.h>

#define D 128

typedef short bfrag __attribute__((ext_vector_type(8)));      // 8 bf16 = 4 VGPRs
typedef float f32x4 __attribute__((ext_vector_type(4)));
typedef unsigned uint32;

// ---------------- bf16 split helpers ----------------
__device__ inline unsigned short bf16_rne(float x) {
    unsigned u = __float_as_uint(x);
    return (unsigned short)((u + 0x7FFFu + ((u >> 16) & 1u)) >> 16);
}
__device__ inline float bf16_to_f(unsigned short h) {
    return __uint_as_float(((unsigned)h) << 16);
}
// pair word: hi in bits [15:0], lo in bits [31:16]
__device__ inline unsigned split2p(float x) {
    unsigned short hi = bf16_rne(x);
    unsigned short lo = bf16_rne(x - bf16_to_f(hi));
    return (unsigned)hi | ((unsigned)lo << 16);
}

// unpack 8 pair-words (32B) -> ah (8 hi bf16), al (8 lo bf16)
__device__ inline void unpair(const uint32* __restrict__ p, bfrag& ah, bfrag& al) {
    uint4 q0 = *(const uint4*)p;
    uint4 q1 = *(const uint4*)(p + 4);
    union { uint32 u[4]; bfrag b; } H, L;
    H.u[0] = __builtin_amdgcn_perm(q0.y, q0.x, 0x05040100u);
    H.u[1] = __builtin_amdgcn_perm(q0.w, q0.z, 0x05040100u);
    H.u[2] = __builtin_amdgcn_perm(q1.y, q1.x, 0x05040100u);
    H.u[3] = __builtin_amdgcn_perm(q1.w, q1.z, 0x05040100u);
    L.u[0] = __builtin_amdgcn_perm(q0.y, q0.x, 0x07060302u);
    L.u[1] = __builtin_amdgcn_perm(q0.w, q0.z, 0x07060302u);
    L.u[2] = __builtin_amdgcn_perm(q1.y, q1.x, 0x07060302u);
    L.u[3] = __builtin_amdgcn_perm(q1.w, q1.z, 0x07060302u);
    ah = H.b;
    al = L.b;
}

// split 8 fp32 (32B) in-register -> hi/lo bf16 fragments
__device__ inline void split8(const float* __restrict__ p, bfrag& ah, bfrag& al) {
    float4 f0 = *(const float4*)p;
    float4 f1 = *(const float4*)(p + 4);
    float v[8] = {f0.x, f0.y, f0.z, f0.w, f1.x, f1.y, f1.z, f1.w};
    union { unsigned short us[8]; bfrag b; } H, L;
    #pragma unroll
    for (int i = 0; i < 8; i++) {
        unsigned pr = split2p(v[i]);
        H.us[i] = (unsigned short)pr;
        L.us[i] = (unsigned short)(pr >> 16);
    }
    ah = H.b;
    al = L.b;
}

// ---------------- edge dtype detection (+ deg/hist zero) ----------------
__global__ __launch_bounds__(256) void detect_mode(const int* __restrict__ e, int* __restrict__ mode,
                                                   int* __restrict__ deg, int* __restrict__ hist, int E, int N) {
    int gid = blockIdx.x * 256 + threadIdx.x;
    int stride = gridDim.x * 256;
    for (int i = gid; i < N; i += stride) deg[i] = 0;
    if (gid < 256) hist[gid] = 0;
    int found = 0;
    for (int p = gid; p < E; p += stride)
        if (e[2 * p + 1] != 0) found = 1;
    if (found) atomicOr(mode, 1);   // 1 => int32, 0 => int64
}

// repack + fused degree count (dst half)
__global__ __launch_bounds__(256) void repack_deg(const void* __restrict__ eraw, const int* __restrict__ mode,
                                                  int* __restrict__ out, int* __restrict__ deg, int E) {
    int i = blockIdx.x * 256 + threadIdx.x;
    if (i >= 2 * E) return;
    int m = *mode;
    int v = m ? ((const int*)eraw)[i] : (int)((const long long*)eraw)[i];
    out[i] = v;
    if (i >= E) atomicAdd(&deg[v], 1);
}

// dinv + degree histogram
__global__ __launch_bounds__(256) void node_hist(const int* __restrict__ deg, float* __restrict__ dinv,
                                                 int* __restrict__ hist, int N) {
    int i = blockIdx.x * 256 + threadIdx.x;
    if (i >= N) return;
    int d = deg[i];
    dinv[i] = 1.0f / sqrtf((float)(d + 1));   // +1 self-loop
    atomicAdd(&hist[min(d, 255)], 1);
}

// dual exclusive scan over 256 bins: binbase (count) in-place, ebase (count*deg); zero bincur
__global__ __launch_bounds__(256) void scan_bins(int* __restrict__ hist, int* __restrict__ ebase,
                                                 int* __restrict__ bincur) {
    __shared__ int s[256], s2[256];
    int t = threadIdx.x;
    int c = hist[t];
    int e = c * t;
    s[t] = c; s2[t] = e;
    __syncthreads();
    for (int off = 1; off < 256; off <<= 1) {
        int a = (t >= off) ? s[t - off] : 0;
        int b = (t >= off) ? s2[t - off] : 0;
        __syncthreads();
        s[t] += a; s2[t] += b;
        __syncthreads();
    }
    hist[t] = s[t] - c;      // exclusive count scan -> binbase
    ebase[t] = s2[t] - e;    // exclusive edge scan
    bincur[t] = 0;
}

// degree-sorted permutation + packed meta + sorted rowbeg
__global__ __launch_bounds__(256) void scatter_perm(const int* __restrict__ deg, const float* __restrict__ dinv,
                                                    const int* __restrict__ binbase, const int* __restrict__ ebase,
                                                    int* __restrict__ bincur, int* __restrict__ tailcur,
                                                    int* __restrict__ rowbeg, int* __restrict__ cursor,
                                                    uint4* __restrict__ meta, int N) {
    int i = blockIdx.x * 256 + threadIdx.x;
    if (i >= N) return;
    int d = deg[i];
    int b = min(d, 255);
    int pib = atomicAdd(&bincur[b], 1);
    int pos = binbase[b] + pib;
    int rb = (b < 255) ? (ebase[b] + pib * b) : (ebase[255] + atomicAdd(tailcur, d));
    rowbeg[i] = rb;
    cursor[i] = 0;
    meta[pos] = make_uint4((unsigned)rb, (unsigned)d, __float_as_uint(dinv[i]), (unsigned)i);
}

// ---------------- CSR fill (counting sort by dst); stores src*16 (float offset) ----------------
__global__ __launch_bounds__(256) void fill_csr(const int* __restrict__ src, const int* __restrict__ dst,
                                                const int* __restrict__ rowbeg, int* __restrict__ cursor,
                                                int* __restrict__ csr_off, int E) {
    int e = blockIdx.x * 256 + threadIdx.x;
    if (e >= E) return;
    int d = dst[e];
    int pos = atomicAdd(&cursor[d], 1);
    csr_off[rowbeg[d] + pos] = src[e] * 16;
}

// ---------------- all weights: transpose + split (4 matrices, one dispatch) ----------------
__global__ __launch_bounds__(256) void prep_w_all(const float* __restrict__ Wpre, const float* __restrict__ W1,
                                                  const float* __restrict__ W2, const float* __restrict__ Wpost,
                                                  unsigned short* __restrict__ preh, unsigned short* __restrict__ prel,
                                                  unsigned short* __restrict__ w1h, unsigned short* __restrict__ w1l,
                                                  unsigned short* __restrict__ w2h, unsigned short* __restrict__ w2l,
                                                  unsigned short* __restrict__ poh, unsigned short* __restrict__ pol) {
    int i = blockIdx.x * 256 + threadIdx.x;
    const float* W; unsigned short *wh, *wl; int idx, ncols;
    if (i < 16384)      { W = Wpre;  wh = preh; wl = prel; idx = i;         ncols = 128; }
    else if (i < 32768) { W = W1;    wh = w1h;  wl = w1l;  idx = i - 16384; ncols = 128; }
    else if (i < 49152) { W = W2;    wh = w2h;  wl = w2l;  idx = i - 32768; ncols = 128; }
    else if (i < 55296) { W = Wpost; wh = poh;  wl = pol;  idx = i - 49152; ncols = 40;  }
    else return;
    int n = idx >> 7, k = idx & 127;
    float v = (n < ncols) ? W[k * ncols + n] : 0.f;
    unsigned p = split2p(v);
    wh[idx] = (unsigned short)p;
    wl[idx] = (unsigned short)(p >> 16);
}

// ---------------- bf16x3 MFMA GEMM ----------------
// AFMT=0: A is pair plane.  AFMT=1: A is fp32 [N][D], split in-register.
// EPI=0: Cf fp32 CHUNKED t'[chunk][row][16] PRE-SCALED by dinv[row].
// EPI=1: bias -> pair plane Pout.  EPI=2: bias + fp32 flat, col<outW mask.
template<int NTILES, int EPI, int AFMT>
__global__ __launch_bounds__(256) void gemm_mfma(const void* __restrict__ Ap,
                                                 const unsigned short* __restrict__ Wth,
                                                 const unsigned short* __restrict__ Wtl,
                                                 const float* __restrict__ bias,
                                                 const float* __restrict__ dinv,
                                                 float* __restrict__ Cf,
                                                 uint32* __restrict__ Pout,
                                                 int nStrips, int N, int outW) {
    int wave = threadIdx.x >> 6;
    int lane = threadIdx.x & 63;
    int l15 = lane & 15, lg = lane >> 4;
    int colbase = blockIdx.y * 64;
    size_t chunkStride = (size_t)nStrips * 256;   // Npad*16 floats per 16-col chunk

    // persistent B fragments: wt[col][k] contiguous in k -> 16B per lane
    bfrag wh[4][NTILES], wl[4][NTILES];
    #pragma unroll
    for (int ks = 0; ks < 4; ks++)
        #pragma unroll
        for (int nt = 0; nt < NTILES; nt++) {
            size_t off = (size_t)(colbase + nt * 16 + l15) * D + ks * 32 + lg * 8;
            wh[ks][nt] = *(const bfrag*)(Wth + off);
            wl[ks][nt] = *(const bfrag*)(Wtl + off);
        }

    for (int strip = blockIdx.x * 4 + wave; strip < nStrips; strip += gridDim.x * 4) {
        int row0 = strip * 16;
        int arow = min(row0 + l15, N - 1);
        bfrag ah[4], al[4];
        #pragma unroll
        for (int ks = 0; ks < 4; ks++) {
            size_t off = (size_t)arow * D + ks * 32 + lg * 8;
            if (AFMT == 0) unpair((const uint32*)Ap + off, ah[ks], al[ks]);
            else           split8((const float*)Ap + off, ah[ks], al[ks]);
        }
        f32x4 acc[NTILES];
        #pragma unroll
        for (int nt = 0; nt < NTILES; nt++) acc[nt] = (f32x4){0.f, 0.f, 0.f, 0.f};
        #pragma unroll
        for (int ks = 0; ks < 4; ks++) {
            #pragma unroll
            for (int nt = 0; nt < NTILES; nt++)
                acc[nt] = __builtin_amdgcn_mfma_f32_16x16x32_bf16(ah[ks], wh[ks][nt], acc[nt], 0, 0, 0);
            #pragma unroll
            for (int nt = 0; nt < NTILES; nt++)
                acc[nt] = __builtin_amdgcn_mfma_f32_16x16x32_bf16(ah[ks], wl[ks][nt], acc[nt], 0, 0, 0);
            #pragma unroll
            for (int nt = 0; nt < NTILES; nt++)
                acc[nt] = __builtin_amdgcn_mfma_f32_16x16x32_bf16(al[ks], wh[ks][nt], acc[nt], 0, 0, 0);
        }
        // pre-scale factors for EPI=0
        float dv[4];
        if (EPI == 0) {
            #pragma unroll
            for (int r = 0; r < 4; r++) {
                int row = row0 + lg * 4 + r;
                dv[r] = (row < N) ? dinv[row] : 0.f;
            }
        }
        // C/D layout (m89-verified): col = lane&15, row = (lane>>4)*4 + reg
        #pragma unroll
        for (int nt = 0; nt < NTILES; nt++) {
            int col = colbase + nt * 16 + l15;
            #pragma unroll
            for (int r = 0; r < 4; r++) {
                int row = row0 + lg * 4 + r;
                if (row >= N) continue;
                float v = acc[nt][r];
                if (EPI == 0) {
                    Cf[(size_t)(col >> 4) * chunkStride + (size_t)row * 16 + (col & 15)] = v * dv[r];
                } else if (EPI == 1) {
                    Pout[(size_t)row * D + col] = split2p(v + bias[col]);
                } else {
                    if (col < outW) Cf[(size_t)row * outW + col] = v + bias[col];
                }
            }
        }
    }
}

// ---------------- XCD-pinned chunked gather, degree-sorted, edge-way parallel ----------------
// chunk = blockIdx.x & 7 pins a contiguous 3.2MB pre-scaled slice t'[chunk] to one XCD's L2.
// Nodes processed in degree-sorted order (meta): uniform trip counts + sequential csr reads.
// 16 lanes/node: 4 col-lanes x 4 edge-ways, 2-deep unroll -> 8 loads in flight/node.
__global__ __launch_bounds__(256) void gather_xcd(const int* __restrict__ csr_off, const uint4* __restrict__ meta,
                                                  const float* __restrict__ t_c, const float* __restrict__ bias,
                                                  uint32* __restrict__ Pout, int N, int nStrips) {
    int chunk = blockIdx.x & 7;
    int k = (blockIdx.x >> 3) * 16 + (threadIdx.x >> 4);   // sorted position
    if (k >= N) return;
    uint4 m = meta[k];
    int beg = (int)m.x;
    int end = beg + (int)m.y;
    float di = __uint_as_float(m.z);
    int node = (int)m.w;
    int w = (threadIdx.x >> 2) & 3;
    int c = threadIdx.x & 3;
    const float* tc = t_c + (size_t)chunk * nStrips * 256 + c * 4;
    float4 a0 = make_float4(0.f, 0.f, 0.f, 0.f);
    float4 a1 = make_float4(0.f, 0.f, 0.f, 0.f);
    int j = beg + w;
    for (; j + 4 < end; j += 8) {
        int o0 = csr_off[j];
        int o1 = csr_off[j + 4];
        float4 v0 = *(const float4*)(tc + o0);
        float4 v1 = *(const float4*)(tc + o1);
        a0.x += v0.x; a0.y += v0.y; a0.z += v0.z; a0.w += v0.w;
        a1.x += v1.x; a1.y += v1.y; a1.z += v1.z; a1.w += v1.w;
    }
    if (j < end) {
        int o0 = csr_off[j];
        float4 v0 = *(const float4*)(tc + o0);
        a0.x += v0.x; a0.y += v0.y; a0.z += v0.z; a0.w += v0.w;
    }
    a0.x += a1.x; a0.y += a1.y; a0.z += a1.z; a0.w += a1.w;
    // combine 4 edge-ways (lane bits 2-3)
    a0.x += __shfl_xor(a0.x, 4); a0.y += __shfl_xor(a0.y, 4);
    a0.z += __shfl_xor(a0.z, 4); a0.w += __shfl_xor(a0.w, 4);
    a0.x += __shfl_xor(a0.x, 8); a0.y += __shfl_xor(a0.y, 8);
    a0.z += __shfl_xor(a0.z, 8); a0.w += __shfl_xor(a0.w, 8);
    if (w != 0) return;
    // t' pre-scaled by dinv: out = dinv[d]*(sum + t'[d]) + b
    float4 tv = *(const float4*)(tc + (size_t)node * 16);
    int col0 = chunk * 16 + c * 4;
    float4 b = *((const float4*)bias + (col0 >> 2));
    float4 r;
    r.x = fmaxf(fmaf(di, a0.x + tv.x, b.x), 0.f);
    r.y = fmaxf(fmaf(di, a0.y + tv.y, b.y), 0.f);
    r.z = fmaxf(fmaf(di, a0.z + tv.z, b.z), 0.f);
    r.w = fmaxf(fmaf(di, a0.w + tv.w, b.w), 0.f);
    uint4 p;
    p.x = split2p(r.x); p.y = split2p(r.y); p.z = split2p(r.z); p.w = split2p(r.w);
    *(uint4*)(Pout + (size_t)node * D + col0) = p;
}

extern "C" void kernel_launch(void* const* d_in, const int* in_sizes, int n_in,
                              void* d_out, int out_size, void* d_ws, size_t ws_size,
                              hipStream_t stream) {
    const float* x      = (const float*)d_in[0];
    const void*  edges  = d_in[1];
    const float* W_pre  = (const float*)d_in[2];
    const float* b_pre  = (const float*)d_in[3];
    const float* W1     = (const float*)d_in[4];
    const float* b1     = (const float*)d_in[5];
    const float* W2     = (const float*)d_in[6];
    const float* b2     = (const float*)d_in[7];
    const float* W_post = (const float*)d_in[8];
    const float* b_post = (const float*)d_in[9];
    float* out = (float*)d_out;

    const int N = in_sizes[0] / D;        // 50000
    const int E = in_sizes[1] / 2;        // 800000
    const int nStrips = (N + 15) / 16;    // 3125
    const int Npad = nStrips * 16;

    // ---- workspace layout (persistent buffers) ----
    char* ws = (char*)d_ws;
    size_t off = 0;
    auto alloc = [&](size_t bytes) { void* p = ws + off; off += (bytes + 255) & ~(size_t)255; return p; };
    uint32* pairA = (uint32*)alloc((size_t)Npad * D * 4);   // pair plane A
    uint32* pairB = (uint32*)alloc((size_t)Npad * D * 4);   // pair plane B
    float*  bufT  = (float*)alloc((size_t)Npad * D * 4);    // chunked pre-scaled t'[8][Npad][16]
    float*  dinv    = (float*)alloc((size_t)N * 4);
    int*    deg     = (int*)alloc((size_t)N * 4);
    int*    rowbeg  = (int*)alloc((size_t)N * 4);
    int*    csr_off = (int*)alloc((size_t)E * 4);
    uint4*  meta    = (uint4*)alloc((size_t)N * 16);
    unsigned short* wpre_h  = (unsigned short*)alloc(128 * 128 * 2);
    unsigned short* wpre_l  = (unsigned short*)alloc(128 * 128 * 2);
    unsigned short* w1_h    = (unsigned short*)alloc(128 * 128 * 2);
    unsigned short* w1_l    = (unsigned short*)alloc(128 * 128 * 2);
    unsigned short* w2_h    = (unsigned short*)alloc(128 * 128 * 2);
    unsigned short* w2_l    = (unsigned short*)alloc(128 * 128 * 2);
    unsigned short* wpost_h = (unsigned short*)alloc(48 * 128 * 2);
    unsigned short* wpost_l = (unsigned short*)alloc(48 * 128 * 2);

    // ---- prep-phase temporaries OVERLAY bufT (dead before first bufT write) ----
    {
        char* t = (char*)bufT;
        size_t toff = 0;
        auto talloc = [&](size_t bytes) { void* p = t + toff; toff += (bytes + 255) & ~(size_t)255; return p; };
        int* srcdst = (int*)talloc((size_t)2 * E * 4);   // 6.4 MB
        int* cursor = (int*)talloc((size_t)N * 4);
        int* mode2  = (int*)talloc(256);                 // [0]=mode, [1]=tail edge cursor
        int* hist   = (int*)talloc(1024);                // 256 bins -> binbase after scan
        int* ebase  = (int*)talloc(1024);
        int* bincur = (int*)talloc(1024);
        int* src = srcdst;
        int* dst = srcdst + E;
        int* mode = mode2;
        int* tailcur = mode2 + 1;

        (void)hipMemsetAsync(mode2, 0, 8, stream);
        detect_mode<<<512, 256, 0, stream>>>((const int*)edges, mode, deg, hist, E, N);
        repack_deg<<<(2 * E + 255) / 256, 256, 0, stream>>>(edges, mode, srcdst, deg, E);
        node_hist<<<(N + 255) / 256, 256, 0, stream>>>(deg, dinv, hist, N);
        scan_bins<<<1, 256, 0, stream>>>(hist, ebase, bincur);
        scatter_perm<<<(N + 255) / 256, 256, 0, stream>>>(deg, dinv, hist, ebase, bincur, tailcur,
                                                          rowbeg, cursor, meta, N);
        fill_csr<<<(E + 255) / 256, 256, 0, stream>>>(src, dst, rowbeg, cursor, csr_off, E);
    }

    // weights: transpose + split, one dispatch
    prep_w_all<<<216, 256, 0, stream>>>(W_pre, W1, W2, W_post,
                                        wpre_h, wpre_l, w1_h, w1_l, w2_h, w2_l, wpost_h, wpost_l);

    const int nGatherBlocks = ((N + 15) / 16) * 8;   // 3125 node-blocks x 8 XCD chunks
    dim3 g128(391, 2);   // 2 strips/wave, 2 column-halves

    // pre MLP: h1(pairB) = x @ W_pre + b_pre  (x split in-register)
    gemm_mfma<4, 1, 1><<<g128, 256, 0, stream>>>(x, wpre_h, wpre_l, b_pre, nullptr, nullptr, pairB, nStrips, N, D);

    // conv1: t' = dinv*(h1 @ W1) (chunked) ; h2(pairA) = relu(dinv*(gather+self) + b1)
    gemm_mfma<4, 0, 0><<<g128, 256, 0, stream>>>(pairB, w1_h, w1_l, nullptr, dinv, bufT, nullptr, nStrips, N, D);
    gather_xcd<<<nGatherBlocks, 256, 0, stream>>>(csr_off, meta, bufT, b1, pairA, N, nStrips);

    // conv2
    gemm_mfma<4, 0, 0><<<g128, 256, 0, stream>>>(pairA, w2_h, w2_l, nullptr, dinv, bufT, nullptr, nStrips, N, D);
    gather_xcd<<<nGatherBlocks, 256, 0, stream>>>(csr_off, meta, bufT, b2, pairB, N, nStrips);

    // post MLP: out = h3 @ W_post + b_post  (40 cols, padded to 48)
    gemm_mfma<3, 2, 0><<<dim3(391, 1), 256, 0, stream>>>(pairB, wpost_h, wpost_l, b_post, nullptr, out, nullptr, nStrips, N, 40);
}

// Round 10
// 391.496 us; speedup vs baseline: 1.5414x; 1.5414x over previous
//
#include <hip/hip_runtime.h>

#define D 128

typedef short bfrag __attribute__((ext_vector_type(8)));      // 8 bf16 = 4 VGPRs
typedef float f32x4 __attribute__((ext_vector_type(4)));
typedef unsigned uint32;

// ---------------- bf16 split helpers ----------------
__device__ inline unsigned short bf16_rne(float x) {
    unsigned u = __float_as_uint(x);
    return (unsigned short)((u + 0x7FFFu + ((u >> 16) & 1u)) >> 16);
}
__device__ inline float bf16_to_f(unsigned short h) {
    return __uint_as_float(((unsigned)h) << 16);
}
// pair word: hi in bits [15:0], lo in bits [31:16]
__device__ inline unsigned split2p(float x) {
    unsigned short hi = bf16_rne(x);
    unsigned short lo = bf16_rne(x - bf16_to_f(hi));
    return (unsigned)hi | ((unsigned)lo << 16);
}

// unpack 8 pair-words (32B) -> ah (8 hi bf16), al (8 lo bf16)
__device__ inline void unpair(const uint32* __restrict__ p, bfrag& ah, bfrag& al) {
    uint4 q0 = *(const uint4*)p;
    uint4 q1 = *(const uint4*)(p + 4);
    union { uint32 u[4]; bfrag b; } H, L;
    H.u[0] = __builtin_amdgcn_perm(q0.y, q0.x, 0x05040100u);
    H.u[1] = __builtin_amdgcn_perm(q0.w, q0.z, 0x05040100u);
    H.u[2] = __builtin_amdgcn_perm(q1.y, q1.x, 0x05040100u);
    H.u[3] = __builtin_amdgcn_perm(q1.w, q1.z, 0x05040100u);
    L.u[0] = __builtin_amdgcn_perm(q0.y, q0.x, 0x07060302u);
    L.u[1] = __builtin_amdgcn_perm(q0.w, q0.z, 0x07060302u);
    L.u[2] = __builtin_amdgcn_perm(q1.y, q1.x, 0x07060302u);
    L.u[3] = __builtin_amdgcn_perm(q1.w, q1.z, 0x07060302u);
    ah = H.b;
    al = L.b;
}

// split 8 fp32 (32B) in-register -> hi/lo bf16 fragments
__device__ inline void split8(const float* __restrict__ p, bfrag& ah, bfrag& al) {
    float4 f0 = *(const float4*)p;
    float4 f1 = *(const float4*)(p + 4);
    float v[8] = {f0.x, f0.y, f0.z, f0.w, f1.x, f1.y, f1.z, f1.w};
    union { unsigned short us[8]; bfrag b; } H, L;
    #pragma unroll
    for (int i = 0; i < 8; i++) {
        unsigned pr = split2p(v[i]);
        H.us[i] = (unsigned short)pr;
        L.us[i] = (unsigned short)(pr >> 16);
    }
    ah = H.b;
    al = L.b;
}

// ---------------- edge dtype detection (+ deg zero) ----------------
__global__ __launch_bounds__(256) void detect_mode(const int* __restrict__ e, int* __restrict__ mode,
                                                   int* __restrict__ deg, int E, int N) {
    int gid = blockIdx.x * 256 + threadIdx.x;
    int stride = gridDim.x * 256;
    for (int i = gid; i < N; i += stride) deg[i] = 0;
    int found = 0;
    for (int p = gid; p < E; p += stride)
        if (e[2 * p + 1] != 0) found = 1;
    if (found) atomicOr(mode, 1);   // 1 => int32, 0 => int64
}

// repack + fused degree count (dst half)
__global__ __launch_bounds__(256) void repack_deg(const void* __restrict__ eraw, const int* __restrict__ mode,
                                                  int* __restrict__ out, int* __restrict__ deg, int E) {
    int i = blockIdx.x * 256 + threadIdx.x;
    if (i >= 2 * E) return;
    int m = *mode;
    int v = m ? ((const int*)eraw)[i] : (int)((const long long*)eraw)[i];
    out[i] = v;
    if (i >= E) atomicAdd(&deg[v], 1);
}

// ---- contention-free degree-bucket ranking (counting sort, hierarchical) ----
// A: per-block LDS histogram + local rank; dinv
__global__ __launch_bounds__(256) void rank_block(const int* __restrict__ deg, float* __restrict__ dinv,
                                                  int* __restrict__ local_rank, int* __restrict__ hist_blk, int N) {
    __shared__ int h[256];
    int t = threadIdx.x;
    h[t] = 0;
    __syncthreads();
    int i = blockIdx.x * 256 + t;
    if (i < N) {
        int d = deg[i];
        dinv[i] = 1.0f / sqrtf((float)(d + 1));   // +1 self-loop
        int b = min(d, 255);
        local_rank[i] = atomicAdd(&h[b], 1);      // LDS atomic: intra-block only
    }
    __syncthreads();
    hist_blk[blockIdx.x * 256 + t] = h[t];
}

// B: thread b scans bin b across blocks (-> per-block exclusive offsets in place),
//    then LDS dual-scan over bins -> binbase (count) and ebase (edges)
__global__ __launch_bounds__(256) void scan_blocks(int* __restrict__ hist_blk, int* __restrict__ binbase,
                                                   int* __restrict__ ebase, int nblk) {
    int b = threadIdx.x;
    int sum = 0;
    for (int k = 0; k < nblk; k++) {
        int v = hist_blk[k * 256 + b];
        hist_blk[k * 256 + b] = sum;
        sum += v;
    }
    __shared__ int s[256], s2[256];
    int c = sum, e = sum * b;
    s[b] = c; s2[b] = e;
    __syncthreads();
    for (int off = 1; off < 256; off <<= 1) {
        int a0 = (b >= off) ? s[b - off] : 0;
        int a1 = (b >= off) ? s2[b - off] : 0;
        __syncthreads();
        s[b] += a0; s2[b] += a1;
        __syncthreads();
    }
    binbase[b] = s[b] - c;
    ebase[b] = s2[b] - e;
}

// C: emit sorted meta + rowbeg (exact slot arithmetic, no contended atomics)
__global__ __launch_bounds__(256) void emit_perm(const int* __restrict__ deg, const float* __restrict__ dinv,
                                                 const int* __restrict__ local_rank, const int* __restrict__ hist_blk,
                                                 const int* __restrict__ binbase, const int* __restrict__ ebase,
                                                 int* __restrict__ tailcur, int* __restrict__ rowbeg,
                                                 int* __restrict__ cursor, uint4* __restrict__ meta, int N) {
    int i = blockIdx.x * 256 + threadIdx.x;
    if (i >= N) return;
    int d = deg[i];
    int b = min(d, 255);
    int rib = hist_blk[blockIdx.x * 256 + b] + local_rank[i];   // rank within bin
    int pos = binbase[b] + rib;
    int rb = (b < 255) ? (ebase[b] + rib * b) : (ebase[255] + atomicAdd(tailcur, d));
    rowbeg[i] = rb;
    cursor[i] = 0;
    meta[pos] = make_uint4((unsigned)rb, (unsigned)d, __float_as_uint(dinv[i]), (unsigned)i);
}

// ---------------- CSR fill (counting sort by dst); stores src*16 (float offset) ----------------
__global__ __launch_bounds__(256) void fill_csr(const int* __restrict__ src, const int* __restrict__ dst,
                                                const int* __restrict__ rowbeg, int* __restrict__ cursor,
                                                int* __restrict__ csr_off, int E) {
    int e = blockIdx.x * 256 + threadIdx.x;
    if (e >= E) return;
    int d = dst[e];
    int pos = atomicAdd(&cursor[d], 1);
    csr_off[rowbeg[d] + pos] = src[e] * 16;
}

// ---------------- all weights: transpose + split (4 matrices, one dispatch) ----------------
__global__ __launch_bounds__(256) void prep_w_all(const float* __restrict__ Wpre, const float* __restrict__ W1,
                                                  const float* __restrict__ W2, const float* __restrict__ Wpost,
                                                  unsigned short* __restrict__ preh, unsigned short* __restrict__ prel,
                                                  unsigned short* __restrict__ w1h, unsigned short* __restrict__ w1l,
                                                  unsigned short* __restrict__ w2h, unsigned short* __restrict__ w2l,
                                                  unsigned short* __restrict__ poh, unsigned short* __restrict__ pol) {
    int i = blockIdx.x * 256 + threadIdx.x;
    const float* W; unsigned short *wh, *wl; int idx, ncols;
    if (i < 16384)      { W = Wpre;  wh = preh; wl = prel; idx = i;         ncols = 128; }
    else if (i < 32768) { W = W1;    wh = w1h;  wl = w1l;  idx = i - 16384; ncols = 128; }
    else if (i < 49152) { W = W2;    wh = w2h;  wl = w2l;  idx = i - 32768; ncols = 128; }
    else if (i < 55296) { W = Wpost; wh = poh;  wl = pol;  idx = i - 49152; ncols = 40;  }
    else return;
    int n = idx >> 7, k = idx & 127;
    float v = (n < ncols) ? W[k * ncols + n] : 0.f;
    unsigned p = split2p(v);
    wh[idx] = (unsigned short)p;
    wl[idx] = (unsigned short)(p >> 16);
}

// ---------------- bf16x3 MFMA GEMM ----------------
// AFMT=0: A is pair plane.  AFMT=1: A is fp32 [N][D], split in-register.
// EPI=0: Cf fp32 CHUNKED t'[chunk][row][16] PRE-SCALED by dinv[row].
// EPI=1: bias -> pair plane Pout.  EPI=2: bias + fp32 flat, col<outW mask.
template<int NTILES, int EPI, int AFMT>
__global__ __launch_bounds__(256) void gemm_mfma(const void* __restrict__ Ap,
                                                 const unsigned short* __restrict__ Wth,
                                                 const unsigned short* __restrict__ Wtl,
                                                 const float* __restrict__ bias,
                                                 const float* __restrict__ dinv,
                                                 float* __restrict__ Cf,
                                                 uint32* __restrict__ Pout,
                                                 int nStrips, int N, int outW) {
    int wave = threadIdx.x >> 6;
    int lane = threadIdx.x & 63;
    int l15 = lane & 15, lg = lane >> 4;
    int colbase = blockIdx.y * 64;
    size_t chunkStride = (size_t)nStrips * 256;   // Npad*16 floats per 16-col chunk

    // persistent B fragments: wt[col][k] contiguous in k -> 16B per lane
    bfrag wh[4][NTILES], wl[4][NTILES];
    #pragma unroll
    for (int ks = 0; ks < 4; ks++)
        #pragma unroll
        for (int nt = 0; nt < NTILES; nt++) {
            size_t off = (size_t)(colbase + nt * 16 + l15) * D + ks * 32 + lg * 8;
            wh[ks][nt] = *(const bfrag*)(Wth + off);
            wl[ks][nt] = *(const bfrag*)(Wtl + off);
        }

    for (int strip = blockIdx.x * 4 + wave; strip < nStrips; strip += gridDim.x * 4) {
        int row0 = strip * 16;
        int arow = min(row0 + l15, N - 1);
        bfrag ah[4], al[4];
        #pragma unroll
        for (int ks = 0; ks < 4; ks++) {
            size_t off = (size_t)arow * D + ks * 32 + lg * 8;
            if (AFMT == 0) unpair((const uint32*)Ap + off, ah[ks], al[ks]);
            else           split8((const float*)Ap + off, ah[ks], al[ks]);
        }
        f32x4 acc[NTILES];
        #pragma unroll
        for (int nt = 0; nt < NTILES; nt++) acc[nt] = (f32x4){0.f, 0.f, 0.f, 0.f};
        #pragma unroll
        for (int ks = 0; ks < 4; ks++) {
            #pragma unroll
            for (int nt = 0; nt < NTILES; nt++)
                acc[nt] = __builtin_amdgcn_mfma_f32_16x16x32_bf16(ah[ks], wh[ks][nt], acc[nt], 0, 0, 0);
            #pragma unroll
            for (int nt = 0; nt < NTILES; nt++)
                acc[nt] = __builtin_amdgcn_mfma_f32_16x16x32_bf16(ah[ks], wl[ks][nt], acc[nt], 0, 0, 0);
            #pragma unroll
            for (int nt = 0; nt < NTILES; nt++)
                acc[nt] = __builtin_amdgcn_mfma_f32_16x16x32_bf16(al[ks], wh[ks][nt], acc[nt], 0, 0, 0);
        }
        // pre-scale factors for EPI=0
        float dv[4];
        if (EPI == 0) {
            #pragma unroll
            for (int r = 0; r < 4; r++) {
                int row = row0 + lg * 4 + r;
                dv[r] = (row < N) ? dinv[row] : 0.f;
            }
        }
        // C/D layout (m89-verified): col = lane&15, row = (lane>>4)*4 + reg
        #pragma unroll
        for (int nt = 0; nt < NTILES; nt++) {
            int col = colbase + nt * 16 + l15;
            #pragma unroll
            for (int r = 0; r < 4; r++) {
                int row = row0 + lg * 4 + r;
                if (row >= N) continue;
                float v = acc[nt][r];
                if (EPI == 0) {
                    Cf[(size_t)(col >> 4) * chunkStride + (size_t)row * 16 + (col & 15)] = v * dv[r];
                } else if (EPI == 1) {
                    Pout[(size_t)row * D + col] = split2p(v + bias[col]);
                } else {
                    if (col < outW) Cf[(size_t)row * outW + col] = v + bias[col];
                }
            }
        }
    }
}

// ---------------- XCD-pinned chunked gather, degree-sorted, edge-way parallel ----------------
__global__ __launch_bounds__(256) void gather_xcd(const int* __restrict__ csr_off, const uint4* __restrict__ meta,
                                                  const float* __restrict__ t_c, const float* __restrict__ bias,
                                                  uint32* __restrict__ Pout, int N, int nStrips) {
    int chunk = blockIdx.x & 7;
    int k = (blockIdx.x >> 3) * 16 + (threadIdx.x >> 4);   // sorted position
    if (k >= N) return;
    uint4 m = meta[k];
    int beg = (int)m.x;
    int end = beg + (int)m.y;
    float di = __uint_as_float(m.z);
    int node = (int)m.w;
    int w = (threadIdx.x >> 2) & 3;
    int c = threadIdx.x & 3;
    const float* tc = t_c + (size_t)chunk * nStrips * 256 + c * 4;
    float4 a0 = make_float4(0.f, 0.f, 0.f, 0.f);
    float4 a1 = make_float4(0.f, 0.f, 0.f, 0.f);
    int j = beg + w;
    for (; j + 4 < end; j += 8) {
        int o0 = csr_off[j];
        int o1 = csr_off[j + 4];
        float4 v0 = *(const float4*)(tc + o0);
        float4 v1 = *(const float4*)(tc + o1);
        a0.x += v0.x; a0.y += v0.y; a0.z += v0.z; a0.w += v0.w;
        a1.x += v1.x; a1.y += v1.y; a1.z += v1.z; a1.w += v1.w;
    }
    if (j < end) {
        int o0 = csr_off[j];
        float4 v0 = *(const float4*)(tc + o0);
        a0.x += v0.x; a0.y += v0.y; a0.z += v0.z; a0.w += v0.w;
    }
    a0.x += a1.x; a0.y += a1.y; a0.z += a1.z; a0.w += a1.w;
    // combine 4 edge-ways (lane bits 2-3)
    a0.x += __shfl_xor(a0.x, 4); a0.y += __shfl_xor(a0.y, 4);
    a0.z += __shfl_xor(a0.z, 4); a0.w += __shfl_xor(a0.w, 4);
    a0.x += __shfl_xor(a0.x, 8); a0.y += __shfl_xor(a0.y, 8);
    a0.z += __shfl_xor(a0.z, 8); a0.w += __shfl_xor(a0.w, 8);
    if (w != 0) return;
    // t' pre-scaled by dinv: out = dinv[d]*(sum + t'[d]) + b
    float4 tv = *(const float4*)(tc + (size_t)node * 16);
    int col0 = chunk * 16 + c * 4;
    float4 b = *((const float4*)bias + (col0 >> 2));
    float4 r;
    r.x = fmaxf(fmaf(di, a0.x + tv.x, b.x), 0.f);
    r.y = fmaxf(fmaf(di, a0.y + tv.y, b.y), 0.f);
    r.z = fmaxf(fmaf(di, a0.z + tv.z, b.z), 0.f);
    r.w = fmaxf(fmaf(di, a0.w + tv.w, b.w), 0.f);
    uint4 p;
    p.x = split2p(r.x); p.y = split2p(r.y); p.z = split2p(r.z); p.w = split2p(r.w);
    *(uint4*)(Pout + (size_t)node * D + col0) = p;
}

extern "C" void kernel_launch(void* const* d_in, const int* in_sizes, int n_in,
                              void* d_out, int out_size, void* d_ws, size_t ws_size,
                              hipStream_t stream) {
    const float* x      = (const float*)d_in[0];
    const void*  edges  = d_in[1];
    const float* W_pre  = (const float*)d_in[2];
    const float* b_pre  = (const float*)d_in[3];
    const float* W1     = (const float*)d_in[4];
    const float* b1     = (const float*)d_in[5];
    const float* W2     = (const float*)d_in[6];
    const float* b2     = (const float*)d_in[7];
    const float* W_post = (const float*)d_in[8];
    const float* b_post = (const float*)d_in[9];
    float* out = (float*)d_out;

    const int N = in_sizes[0] / D;        // 50000
    const int E = in_sizes[1] / 2;        // 800000
    const int nStrips = (N + 15) / 16;    // 3125
    const int Npad = nStrips * 16;
    const int nBlk = (N + 255) / 256;     // 196

    // ---- workspace layout (persistent buffers) ----
    char* ws = (char*)d_ws;
    size_t off = 0;
    auto alloc = [&](size_t bytes) { void* p = ws + off; off += (bytes + 255) & ~(size_t)255; return p; };
    uint32* pairA = (uint32*)alloc((size_t)Npad * D * 4);   // pair plane A
    uint32* pairB = (uint32*)alloc((size_t)Npad * D * 4);   // pair plane B
    float*  bufT  = (float*)alloc((size_t)Npad * D * 4);    // chunked pre-scaled t'[8][Npad][16]
    float*  dinv    = (float*)alloc((size_t)N * 4);
    int*    deg     = (int*)alloc((size_t)N * 4);
    int*    rowbeg  = (int*)alloc((size_t)N * 4);
    int*    csr_off = (int*)alloc((size_t)E * 4);
    uint4*  meta    = (uint4*)alloc((size_t)N * 16);
    unsigned short* wpre_h  = (unsigned short*)alloc(128 * 128 * 2);
    unsigned short* wpre_l  = (unsigned short*)alloc(128 * 128 * 2);
    unsigned short* w1_h    = (unsigned short*)alloc(128 * 128 * 2);
    unsigned short* w1_l    = (unsigned short*)alloc(128 * 128 * 2);
    unsigned short* w2_h    = (unsigned short*)alloc(128 * 128 * 2);
    unsigned short* w2_l    = (unsigned short*)alloc(128 * 128 * 2);
    unsigned short* wpost_h = (unsigned short*)alloc(48 * 128 * 2);
    unsigned short* wpost_l = (unsigned short*)alloc(48 * 128 * 2);

    // ---- prep-phase temporaries OVERLAY bufT (dead before first bufT write) ----
    {
        char* t = (char*)bufT;
        size_t toff = 0;
        auto talloc = [&](size_t bytes) { void* p = t + toff; toff += (bytes + 255) & ~(size_t)255; return p; };
        int* srcdst     = (int*)talloc((size_t)2 * E * 4);      // 6.4 MB
        int* cursor     = (int*)talloc((size_t)N * 4);
        int* local_rank = (int*)talloc((size_t)N * 4);
        int* hist_blk   = (int*)talloc((size_t)nBlk * 256 * 4); // ~200 KB
        int* mode2      = (int*)talloc(256);                    // [0]=mode, [1]=tail cursor
        int* binbase    = (int*)talloc(1024);
        int* ebase      = (int*)talloc(1024);
        int* src = srcdst;
        int* dst = srcdst + E;
        int* mode = mode2;
        int* tailcur = mode2 + 1;

        (void)hipMemsetAsync(mode2, 0, 8, stream);
        detect_mode<<<512, 256, 0, stream>>>((const int*)edges, mode, deg, E, N);
        repack_deg<<<(2 * E + 255) / 256, 256, 0, stream>>>(edges, mode, srcdst, deg, E);
        rank_block<<<nBlk, 256, 0, stream>>>(deg, dinv, local_rank, hist_blk, N);
        scan_blocks<<<1, 256, 0, stream>>>(hist_blk, binbase, ebase, nBlk);
        emit_perm<<<nBlk, 256, 0, stream>>>(deg, dinv, local_rank, hist_blk, binbase, ebase,
                                            tailcur, rowbeg, cursor, meta, N);
        fill_csr<<<(E + 255) / 256, 256, 0, stream>>>(src, dst, rowbeg, cursor, csr_off, E);
    }

    // weights: transpose + split, one dispatch
    prep_w_all<<<216, 256, 0, stream>>>(W_pre, W1, W2, W_post,
                                        wpre_h, wpre_l, w1_h, w1_l, w2_h, w2_l, wpost_h, wpost_l);

    const int nGatherBlocks = ((N + 15) / 16) * 8;   // 3125 node-blocks x 8 XCD chunks
    dim3 g128(391, 2);   // 2 strips/wave, 2 column-halves

    // pre MLP: h1(pairB) = x @ W_pre + b_pre  (x split in-register)
    gemm_mfma<4, 1, 1><<<g128, 256, 0, stream>>>(x, wpre_h, wpre_l, b_pre, nullptr, nullptr, pairB, nStrips, N, D);

    // conv1: t' = dinv*(h1 @ W1) (chunked) ; h2(pairA) = relu(dinv*(gather+self) + b1)
    gemm_mfma<4, 0, 0><<<g128, 256, 0, stream>>>(pairB, w1_h, w1_l, nullptr, dinv, bufT, nullptr, nStrips, N, D);
    gather_xcd<<<nGatherBlocks, 256, 0, stream>>>(csr_off, meta, bufT, b1, pairA, N, nStrips);

    // conv2
    gemm_mfma<4, 0, 0><<<g128, 256, 0, stream>>>(pairA, w2_h, w2_l, nullptr, dinv, bufT, nullptr, nStrips, N, D);
    gather_xcd<<<nGatherBlocks, 256, 0, stream>>>(csr_off, meta, bufT, b2, pairB, N, nStrips);

    // post MLP: out = h3 @ W_post + b_post  (40 cols, padded to 48)
    gemm_mfma<3, 2, 0><<<dim3(391, 1), 256, 0, stream>>>(pairB, wpost_h, wpost_l, b_post, nullptr, out, nullptr, nStrips, N, 40);
}

// Round 11
// 333.922 us; speedup vs baseline: 1.8072x; 1.1724x over previous
//
#include <hip/hip_runtime.h>

#define D 128

typedef short bfrag __attribute__((ext_vector_type(8)));      // 8 bf16 = 4 VGPRs
typedef float f32x4 __attribute__((ext_vector_type(4)));
typedef unsigned uint32;

// ---------------- bf16 split helpers ----------------
__device__ inline unsigned short bf16_rne(float x) {
    unsigned u = __float_as_uint(x);
    return (unsigned short)((u + 0x7FFFu + ((u >> 16) & 1u)) >> 16);
}
__device__ inline float bf16_to_f(unsigned short h) {
    return __uint_as_float(((unsigned)h) << 16);
}
// pair word: hi in bits [15:0], lo in bits [31:16]
__device__ inline unsigned split2p(float x) {
    unsigned short hi = bf16_rne(x);
    unsigned short lo = bf16_rne(x - bf16_to_f(hi));
    return (unsigned)hi | ((unsigned)lo << 16);
}

// unpack 8 pair-words (2x uint4 regs) -> ah (8 hi bf16), al (8 lo bf16)
__device__ inline void unpair_r(uint4 q0, uint4 q1, bfrag& ah, bfrag& al) {
    union { uint32 u[4]; bfrag b; } H, L;
    H.u[0] = __builtin_amdgcn_perm(q0.y, q0.x, 0x05040100u);
    H.u[1] = __builtin_amdgcn_perm(q0.w, q0.z, 0x05040100u);
    H.u[2] = __builtin_amdgcn_perm(q1.y, q1.x, 0x05040100u);
    H.u[3] = __builtin_amdgcn_perm(q1.w, q1.z, 0x05040100u);
    L.u[0] = __builtin_amdgcn_perm(q0.y, q0.x, 0x07060302u);
    L.u[1] = __builtin_amdgcn_perm(q0.w, q0.z, 0x07060302u);
    L.u[2] = __builtin_amdgcn_perm(q1.y, q1.x, 0x07060302u);
    L.u[3] = __builtin_amdgcn_perm(q1.w, q1.z, 0x07060302u);
    ah = H.b;
    al = L.b;
}

// split 8 fp32 (2x uint4 regs, bit-cast) -> hi/lo bf16 fragments
__device__ inline void split8_r(uint4 q0, uint4 q1, bfrag& ah, bfrag& al) {
    float v[8] = {__uint_as_float(q0.x), __uint_as_float(q0.y), __uint_as_float(q0.z), __uint_as_float(q0.w),
                  __uint_as_float(q1.x), __uint_as_float(q1.y), __uint_as_float(q1.z), __uint_as_float(q1.w)};
    union { unsigned short us[8]; bfrag b; } H, L;
    #pragma unroll
    for (int i = 0; i < 8; i++) {
        unsigned pr = split2p(v[i]);
        H.us[i] = (unsigned short)pr;
        L.us[i] = (unsigned short)(pr >> 16);
    }
    ah = H.b;
    al = L.b;
}

// ---------------- edge dtype detection (+ deg zero) ----------------
__global__ __launch_bounds__(256) void detect_mode(const int* __restrict__ e, int* __restrict__ mode,
                                                   int* __restrict__ deg, int E, int N) {
    int gid = blockIdx.x * 256 + threadIdx.x;
    int stride = gridDim.x * 256;
    for (int i = gid; i < N; i += stride) deg[i] = 0;
    int found = 0;
    for (int p = gid; p < E; p += stride)
        if (e[2 * p + 1] != 0) found = 1;
    if (found) atomicOr(mode, 1);   // 1 => int32, 0 => int64
}

// repack + fused degree count (dst half)
__global__ __launch_bounds__(256) void repack_deg(const void* __restrict__ eraw, const int* __restrict__ mode,
                                                  int* __restrict__ out, int* __restrict__ deg, int E) {
    int i = blockIdx.x * 256 + threadIdx.x;
    if (i >= 2 * E) return;
    int m = *mode;
    int v = m ? ((const int*)eraw)[i] : (int)((const long long*)eraw)[i];
    out[i] = v;
    if (i >= E) atomicAdd(&deg[v], 1);
}

// ---- contention-free degree-bucket ranking (counting sort, hierarchical) ----
// A: per-block LDS histogram + local rank; dinv
__global__ __launch_bounds__(256) void rank_block(const int* __restrict__ deg, float* __restrict__ dinv,
                                                  int* __restrict__ local_rank, int* __restrict__ hist_blk, int N) {
    __shared__ int h[256];
    int t = threadIdx.x;
    h[t] = 0;
    __syncthreads();
    int i = blockIdx.x * 256 + t;
    if (i < N) {
        int d = deg[i];
        dinv[i] = 1.0f / sqrtf((float)(d + 1));   // +1 self-loop
        int b = min(d, 255);
        local_rank[i] = atomicAdd(&h[b], 1);      // LDS atomic: intra-block only
    }
    __syncthreads();
    hist_blk[blockIdx.x * 256 + t] = h[t];
}

// B: thread b scans bin b across blocks (8-unrolled: 8 loads in flight),
//    then LDS dual-scan over bins -> binbase (count) and ebase (edges)
__global__ __launch_bounds__(256) void scan_blocks(int* __restrict__ hist_blk, int* __restrict__ binbase,
                                                   int* __restrict__ ebase, int nblk) {
    int b = threadIdx.x;
    int sum = 0;
    int k = 0;
    for (; k + 8 <= nblk; k += 8) {
        int v[8];
        #pragma unroll
        for (int u = 0; u < 8; u++) v[u] = hist_blk[(k + u) * 256 + b];
        #pragma unroll
        for (int u = 0; u < 8; u++) { hist_blk[(k + u) * 256 + b] = sum; sum += v[u]; }
    }
    for (; k < nblk; k++) {
        int v = hist_blk[k * 256 + b];
        hist_blk[k * 256 + b] = sum;
        sum += v;
    }
    __shared__ int s[256], s2[256];
    int c = sum, e = sum * b;
    s[b] = c; s2[b] = e;
    __syncthreads();
    for (int off = 1; off < 256; off <<= 1) {
        int a0 = (b >= off) ? s[b - off] : 0;
        int a1 = (b >= off) ? s2[b - off] : 0;
        __syncthreads();
        s[b] += a0; s2[b] += a1;
        __syncthreads();
    }
    binbase[b] = s[b] - c;
    ebase[b] = s2[b] - e;
}

// C: emit sorted meta + rowbeg (exact slot arithmetic, no contended atomics)
__global__ __launch_bounds__(256) void emit_perm(const int* __restrict__ deg, const float* __restrict__ dinv,
                                                 const int* __restrict__ local_rank, const int* __restrict__ hist_blk,
                                                 const int* __restrict__ binbase, const int* __restrict__ ebase,
                                                 int* __restrict__ tailcur, int* __restrict__ rowbeg,
                                                 int* __restrict__ cursor, uint4* __restrict__ meta, int N) {
    int i = blockIdx.x * 256 + threadIdx.x;
    if (i >= N) return;
    int d = deg[i];
    int b = min(d, 255);
    int rib = hist_blk[blockIdx.x * 256 + b] + local_rank[i];   // rank within bin
    int pos = binbase[b] + rib;
    int rb = (b < 255) ? (ebase[b] + rib * b) : (ebase[255] + atomicAdd(tailcur, d));
    rowbeg[i] = rb;
    cursor[i] = 0;
    meta[pos] = make_uint4((unsigned)rb, (unsigned)d, __float_as_uint(dinv[i]), (unsigned)i);
}

// ---------------- CSR fill (counting sort by dst); src fits ushort (N < 65536) ----------------
__global__ __launch_bounds__(256) void fill_csr(const int* __restrict__ src, const int* __restrict__ dst,
                                                const int* __restrict__ rowbeg, int* __restrict__ cursor,
                                                unsigned short* __restrict__ csr16, int E) {
    int e = blockIdx.x * 256 + threadIdx.x;
    if (e >= E) return;
    int d = dst[e];
    int pos = atomicAdd(&cursor[d], 1);
    csr16[rowbeg[d] + pos] = (unsigned short)src[e];
}

// ---------------- all weights: transpose + split (4 matrices, one dispatch) ----------------
__global__ __launch_bounds__(256) void prep_w_all(const float* __restrict__ Wpre, const float* __restrict__ W1,
                                                  const float* __restrict__ W2, const float* __restrict__ Wpost,
                                                  unsigned short* __restrict__ preh, unsigned short* __restrict__ prel,
                                                  unsigned short* __restrict__ w1h, unsigned short* __restrict__ w1l,
                                                  unsigned short* __restrict__ w2h, unsigned short* __restrict__ w2l,
                                                  unsigned short* __restrict__ poh, unsigned short* __restrict__ pol) {
    int i = blockIdx.x * 256 + threadIdx.x;
    const float* W; unsigned short *wh, *wl; int idx, ncols;
    if (i < 16384)      { W = Wpre;  wh = preh; wl = prel; idx = i;         ncols = 128; }
    else if (i < 32768) { W = W1;    wh = w1h;  wl = w1l;  idx = i - 16384; ncols = 128; }
    else if (i < 49152) { W = W2;    wh = w2h;  wl = w2l;  idx = i - 32768; ncols = 128; }
    else if (i < 55296) { W = Wpost; wh = poh;  wl = pol;  idx = i - 49152; ncols = 40;  }
    else return;
    int n = idx >> 7, k = idx & 127;
    float v = (n < ncols) ? W[k * ncols + n] : 0.f;
    unsigned p = split2p(v);
    wh[idx] = (unsigned short)p;
    wl[idx] = (unsigned short)(p >> 16);
}

// ---------------- bf16x3 MFMA GEMM, software-pipelined ----------------
// Col group on blockIdx.x (adjacent dispatch -> shared A lines in L2); strips on blockIdx.y.
// Next strip's A staged as raw uint4 BEFORE current strip's MFMA (load latency hidden).
// AFMT=0: A is pair plane. AFMT=1: A is fp32 (split in-register).
// EPI=0: Cf fp32 CHUNKED t'[chunk][row][16] PRE-SCALED by dinv[row].
// EPI=1: bias -> pair plane Pout.  EPI=2: bias + fp32 flat, col<outW mask.
template<int NTILES, int EPI, int AFMT>
__global__ __launch_bounds__(256) void gemm_mfma(const void* __restrict__ Ap,
                                                 const unsigned short* __restrict__ Wth,
                                                 const unsigned short* __restrict__ Wtl,
                                                 const float* __restrict__ bias,
                                                 const float* __restrict__ dinv,
                                                 float* __restrict__ Cf,
                                                 uint32* __restrict__ Pout,
                                                 int nStrips, int N, int outW) {
    int wave = threadIdx.x >> 6;
    int lane = threadIdx.x & 63;
    int l15 = lane & 15, lg = lane >> 4;
    int colbase = blockIdx.x * 64;
    size_t chunkStride = (size_t)nStrips * 256;   // Npad*16 floats per 16-col chunk

    // persistent B fragments: wt[col][k] contiguous in k -> 16B per lane
    bfrag wh[4][NTILES], wl[4][NTILES];
    #pragma unroll
    for (int ks = 0; ks < 4; ks++)
        #pragma unroll
        for (int nt = 0; nt < NTILES; nt++) {
            size_t off = (size_t)(colbase + nt * 16 + l15) * D + ks * 32 + lg * 8;
            wh[ks][nt] = *(const bfrag*)(Wth + off);
            wl[ks][nt] = *(const bfrag*)(Wtl + off);
        }

    const int stride = gridDim.y * 4;
    int strip = blockIdx.y * 4 + wave;
    if (strip >= nStrips) return;

    // raw A staging: 8x uint4 per strip (4 ks x 32B)
    uint4 cur[8];
    auto loadraw = [&](int s, uint4* r) {
        int arow = min(s * 16 + l15, N - 1);
        const uint4* p = (const uint4*)Ap + (size_t)arow * 32 + lg * 2;
        #pragma unroll
        for (int ks = 0; ks < 4; ks++) {
            r[2 * ks]     = p[ks * 8];
            r[2 * ks + 1] = p[ks * 8 + 1];
        }
    };

    loadraw(strip, cur);
    while (true) {
        int next = strip + stride;
        bool has_next = next < nStrips;
        uint4 nxt[8];
        if (has_next) loadraw(next, nxt);   // issue next loads before MFMA

        bfrag ah[4], al[4];
        #pragma unroll
        for (int ks = 0; ks < 4; ks++) {
            if (AFMT == 0) unpair_r(cur[2 * ks], cur[2 * ks + 1], ah[ks], al[ks]);
            else           split8_r(cur[2 * ks], cur[2 * ks + 1], ah[ks], al[ks]);
        }
        f32x4 acc[NTILES];
        #pragma unroll
        for (int nt = 0; nt < NTILES; nt++) acc[nt] = (f32x4){0.f, 0.f, 0.f, 0.f};
        #pragma unroll
        for (int ks = 0; ks < 4; ks++) {
            #pragma unroll
            for (int nt = 0; nt < NTILES; nt++)
                acc[nt] = __builtin_amdgcn_mfma_f32_16x16x32_bf16(ah[ks], wh[ks][nt], acc[nt], 0, 0, 0);
            #pragma unroll
            for (int nt = 0; nt < NTILES; nt++)
                acc[nt] = __builtin_amdgcn_mfma_f32_16x16x32_bf16(ah[ks], wl[ks][nt], acc[nt], 0, 0, 0);
            #pragma unroll
            for (int nt = 0; nt < NTILES; nt++)
                acc[nt] = __builtin_amdgcn_mfma_f32_16x16x32_bf16(al[ks], wh[ks][nt], acc[nt], 0, 0, 0);
        }

        int row0 = strip * 16;
        float dv[4];
        if (EPI == 0) {
            #pragma unroll
            for (int r = 0; r < 4; r++) {
                int row = row0 + lg * 4 + r;
                dv[r] = (row < N) ? dinv[row] : 0.f;
            }
        }
        // C/D layout (m89-verified): col = lane&15, row = (lane>>4)*4 + reg
        #pragma unroll
        for (int nt = 0; nt < NTILES; nt++) {
            int col = colbase + nt * 16 + l15;
            #pragma unroll
            for (int r = 0; r < 4; r++) {
                int row = row0 + lg * 4 + r;
                if (row >= N) continue;
                float v = acc[nt][r];
                if (EPI == 0) {
                    Cf[(size_t)(col >> 4) * chunkStride + (size_t)row * 16 + (col & 15)] = v * dv[r];
                } else if (EPI == 1) {
                    Pout[(size_t)row * D + col] = split2p(v + bias[col]);
                } else {
                    if (col < outW) Cf[(size_t)row * outW + col] = v + bias[col];
                }
            }
        }
        if (!has_next) break;
        #pragma unroll
        for (int i = 0; i < 8; i++) cur[i] = nxt[i];
        strip = next;
    }
}

// ---------------- XCD-pinned chunked gather, degree-sorted, 4-deep edge-way parallel ----------------
// chunk = blockIdx.x & 7 pins a contiguous 3.2MB pre-scaled slice t'[chunk] to one XCD's L2.
// 16 lanes/node (4 ways x 4 cols); way w walks j = beg+w, +4, ... 4-deep unrolled ->
// 16 independent t-loads in flight per node; deg<=16 nodes finish in ONE memory round.
__global__ __launch_bounds__(256) void gather_xcd(const unsigned short* __restrict__ csr16,
                                                  const uint4* __restrict__ meta,
                                                  const float* __restrict__ t_c, const float* __restrict__ bias,
                                                  uint32* __restrict__ Pout, int N, int nStrips) {
    int chunk = blockIdx.x & 7;
    int k = (blockIdx.x >> 3) * 16 + (threadIdx.x >> 4);   // sorted position
    if (k >= N) return;
    uint4 m = meta[k];
    int beg = (int)m.x;
    int end = beg + (int)m.y;
    float di = __uint_as_float(m.z);
    int node = (int)m.w;
    int w = (threadIdx.x >> 2) & 3;
    int c = threadIdx.x & 3;
    const float* tc = t_c + (size_t)chunk * nStrips * 256 + c * 4;
    float4 a0 = make_float4(0.f, 0.f, 0.f, 0.f);
    float4 a1 = make_float4(0.f, 0.f, 0.f, 0.f);
    int j = beg + w;
    for (; j + 12 < end; j += 16) {
        int o0 = csr16[j];
        int o1 = csr16[j + 4];
        int o2 = csr16[j + 8];
        int o3 = csr16[j + 12];
        float4 v0 = *(const float4*)(tc + ((size_t)o0 << 4));
        float4 v1 = *(const float4*)(tc + ((size_t)o1 << 4));
        float4 v2 = *(const float4*)(tc + ((size_t)o2 << 4));
        float4 v3 = *(const float4*)(tc + ((size_t)o3 << 4));
        a0.x += v0.x; a0.y += v0.y; a0.z += v0.z; a0.w += v0.w;
        a1.x += v1.x; a1.y += v1.y; a1.z += v1.z; a1.w += v1.w;
        a0.x += v2.x; a0.y += v2.y; a0.z += v2.z; a0.w += v2.w;
        a1.x += v3.x; a1.y += v3.y; a1.z += v3.z; a1.w += v3.w;
    }
    for (; j < end; j += 4) {
        int o0 = csr16[j];
        float4 v0 = *(const float4*)(tc + ((size_t)o0 << 4));
        a0.x += v0.x; a0.y += v0.y; a0.z += v0.z; a0.w += v0.w;
    }
    a0.x += a1.x; a0.y += a1.y; a0.z += a1.z; a0.w += a1.w;
    // combine 4 edge-ways (lane bits 2-3)
    a0.x += __shfl_xor(a0.x, 4); a0.y += __shfl_xor(a0.y, 4);
    a0.z += __shfl_xor(a0.z, 4); a0.w += __shfl_xor(a0.w, 4);
    a0.x += __shfl_xor(a0.x, 8); a0.y += __shfl_xor(a0.y, 8);
    a0.z += __shfl_xor(a0.z, 8); a0.w += __shfl_xor(a0.w, 8);
    if (w != 0) return;
    // t' pre-scaled by dinv: out = dinv[d]*(sum + t'[d]) + b
    float4 tv = *(const float4*)(tc + (size_t)node * 16);
    int col0 = chunk * 16 + c * 4;
    float4 b = *((const float4*)bias + (col0 >> 2));
    float4 r;
    r.x = fmaxf(fmaf(di, a0.x + tv.x, b.x), 0.f);
    r.y = fmaxf(fmaf(di, a0.y + tv.y, b.y), 0.f);
    r.z = fmaxf(fmaf(di, a0.z + tv.z, b.z), 0.f);
    r.w = fmaxf(fmaf(di, a0.w + tv.w, b.w), 0.f);
    uint4 p;
    p.x = split2p(r.x); p.y = split2p(r.y); p.z = split2p(r.z); p.w = split2p(r.w);
    *(uint4*)(Pout + (size_t)node * D + col0) = p;
}

extern "C" void kernel_launch(void* const* d_in, const int* in_sizes, int n_in,
                              void* d_out, int out_size, void* d_ws, size_t ws_size,
                              hipStream_t stream) {
    const float* x      = (const float*)d_in[0];
    const void*  edges  = d_in[1];
    const float* W_pre  = (const float*)d_in[2];
    const float* b_pre  = (const float*)d_in[3];
    const float* W1     = (const float*)d_in[4];
    const float* b1     = (const float*)d_in[5];
    const float* W2     = (const float*)d_in[6];
    const float* b2     = (const float*)d_in[7];
    const float* W_post = (const float*)d_in[8];
    const float* b_post = (const float*)d_in[9];
    float* out = (float*)d_out;

    const int N = in_sizes[0] / D;        // 50000
    const int E = in_sizes[1] / 2;        // 800000
    const int nStrips = (N + 15) / 16;    // 3125
    const int Npad = nStrips * 16;
    const int nBlk = (N + 255) / 256;     // 196

    // ---- workspace layout (persistent buffers) ----
    char* ws = (char*)d_ws;
    size_t off = 0;
    auto alloc = [&](size_t bytes) { void* p = ws + off; off += (bytes + 255) & ~(size_t)255; return p; };
    uint32* pairA = (uint32*)alloc((size_t)Npad * D * 4);   // pair plane A
    uint32* pairB = (uint32*)alloc((size_t)Npad * D * 4);   // pair plane B
    float*  bufT  = (float*)alloc((size_t)Npad * D * 4);    // chunked pre-scaled t'[8][Npad][16]
    float*  dinv    = (float*)alloc((size_t)N * 4);
    int*    deg     = (int*)alloc((size_t)N * 4);
    int*    rowbeg  = (int*)alloc((size_t)N * 4);
    unsigned short* csr16 = (unsigned short*)alloc((size_t)E * 2);
    uint4*  meta    = (uint4*)alloc((size_t)N * 16);
    unsigned short* wpre_h  = (unsigned short*)alloc(128 * 128 * 2);
    unsigned short* wpre_l  = (unsigned short*)alloc(128 * 128 * 2);
    unsigned short* w1_h    = (unsigned short*)alloc(128 * 128 * 2);
    unsigned short* w1_l    = (unsigned short*)alloc(128 * 128 * 2);
    unsigned short* w2_h    = (unsigned short*)alloc(128 * 128 * 2);
    unsigned short* w2_l    = (unsigned short*)alloc(128 * 128 * 2);
    unsigned short* wpost_h = (unsigned short*)alloc(48 * 128 * 2);
    unsigned short* wpost_l = (unsigned short*)alloc(48 * 128 * 2);

    // ---- prep-phase temporaries OVERLAY bufT (dead before first bufT write) ----
    {
        char* t = (char*)bufT;
        size_t toff = 0;
        auto talloc = [&](size_t bytes) { void* p = t + toff; toff += (bytes + 255) & ~(size_t)255; return p; };
        int* srcdst     = (int*)talloc((size_t)2 * E * 4);      // 6.4 MB
        int* cursor     = (int*)talloc((size_t)N * 4);
        int* local_rank = (int*)talloc((size_t)N * 4);
        int* hist_blk   = (int*)talloc((size_t)nBlk * 256 * 4); // ~200 KB
        int* mode2      = (int*)talloc(256);                    // [0]=mode, [1]=tail cursor
        int* binbase    = (int*)talloc(1024);
        int* ebase      = (int*)talloc(1024);
        int* src = srcdst;
        int* dst = srcdst + E;
        int* mode = mode2;
        int* tailcur = mode2 + 1;

        (void)hipMemsetAsync(mode2, 0, 8, stream);
        detect_mode<<<512, 256, 0, stream>>>((const int*)edges, mode, deg, E, N);
        repack_deg<<<(2 * E + 255) / 256, 256, 0, stream>>>(edges, mode, srcdst, deg, E);
        rank_block<<<nBlk, 256, 0, stream>>>(deg, dinv, local_rank, hist_blk, N);
        scan_blocks<<<1, 256, 0, stream>>>(hist_blk, binbase, ebase, nBlk);
        emit_perm<<<nBlk, 256, 0, stream>>>(deg, dinv, local_rank, hist_blk, binbase, ebase,
                                            tailcur, rowbeg, cursor, meta, N);
        fill_csr<<<(E + 255) / 256, 256, 0, stream>>>(src, dst, rowbeg, cursor, csr16, E);
    }

    // weights: transpose + split, one dispatch
    prep_w_all<<<216, 256, 0, stream>>>(W_pre, W1, W2, W_post,
                                        wpre_h, wpre_l, w1_h, w1_l, w2_h, w2_l, wpost_h, wpost_l);

    const int nGatherBlocks = ((N + 15) / 16) * 8;   // 3125 node-blocks x 8 XCD chunks
    dim3 g128(2, 196);   // 2 col-halves (x, adjacent dispatch) x 196 strip-blocks (~4 strips/wave)

    // pre MLP: h1(pairB) = x @ W_pre + b_pre  (x split in-register)
    gemm_mfma<4, 1, 1><<<g128, 256, 0, stream>>>(x, wpre_h, wpre_l, b_pre, nullptr, nullptr, pairB, nStrips, N, D);

    // conv1: t' = dinv*(h1 @ W1) (chunked) ; h2(pairA) = relu(dinv*(gather+self) + b1)
    gemm_mfma<4, 0, 0><<<g128, 256, 0, stream>>>(pairB, w1_h, w1_l, nullptr, dinv, bufT, nullptr, nStrips, N, D);
    gather_xcd<<<nGatherBlocks, 256, 0, stream>>>(csr16, meta, bufT, b1, pairA, N, nStrips);

    // conv2
    gemm_mfma<4, 0, 0><<<g128, 256, 0, stream>>>(pairA, w2_h, w2_l, nullptr, dinv, bufT, nullptr, nStrips, N, D);
    gather_xcd<<<nGatherBlocks, 256, 0, stream>>>(csr16, meta, bufT, b2, pairB, N, nStrips);

    // post MLP: out = h3 @ W_post + b_post  (40 cols, padded to 48)
    gemm_mfma<3, 2, 0><<<dim3(1, 196), 256, 0, stream>>>(pairB, wpost_h, wpost_l, b_post, nullptr, out, nullptr, nStrips, N, 40);
}

// Round 12
// 305.978 us; speedup vs baseline: 1.9723x; 1.0913x over previous
//
#include <hip/hip_runtime.h>

#define D 128

typedef short bfrag __attribute__((ext_vector_type(8)));      // 8 bf16 = 4 VGPRs
typedef float f32x4 __attribute__((ext_vector_type(4)));
typedef unsigned uint32;

// ---------------- bf16 split helpers ----------------
__device__ inline unsigned short bf16_rne(float x) {
    unsigned u = __float_as_uint(x);
    return (unsigned short)((u + 0x7FFFu + ((u >> 16) & 1u)) >> 16);
}
__device__ inline float bf16_to_f(unsigned short h) {
    return __uint_as_float(((unsigned)h) << 16);
}
// pair word: hi in bits [15:0], lo in bits [31:16]
__device__ inline unsigned split2p(float x) {
    unsigned short hi = bf16_rne(x);
    unsigned short lo = bf16_rne(x - bf16_to_f(hi));
    return (unsigned)hi | ((unsigned)lo << 16);
}

// unpack 8 pair-words (2x uint4 regs) -> ah (8 hi bf16), al (8 lo bf16)
__device__ inline void unpair_r(uint4 q0, uint4 q1, bfrag& ah, bfrag& al) {
    union { uint32 u[4]; bfrag b; } H, L;
    H.u[0] = __builtin_amdgcn_perm(q0.y, q0.x, 0x05040100u);
    H.u[1] = __builtin_amdgcn_perm(q0.w, q0.z, 0x05040100u);
    H.u[2] = __builtin_amdgcn_perm(q1.y, q1.x, 0x05040100u);
    H.u[3] = __builtin_amdgcn_perm(q1.w, q1.z, 0x05040100u);
    L.u[0] = __builtin_amdgcn_perm(q0.y, q0.x, 0x07060302u);
    L.u[1] = __builtin_amdgcn_perm(q0.w, q0.z, 0x07060302u);
    L.u[2] = __builtin_amdgcn_perm(q1.y, q1.x, 0x07060302u);
    L.u[3] = __builtin_amdgcn_perm(q1.w, q1.z, 0x07060302u);
    ah = H.b;
    al = L.b;
}

// split 8 fp32 (2x uint4 regs, bit-cast) -> hi/lo bf16 fragments
__device__ inline void split8_r(uint4 q0, uint4 q1, bfrag& ah, bfrag& al) {
    float v[8] = {__uint_as_float(q0.x), __uint_as_float(q0.y), __uint_as_float(q0.z), __uint_as_float(q0.w),
                  __uint_as_float(q1.x), __uint_as_float(q1.y), __uint_as_float(q1.z), __uint_as_float(q1.w)};
    union { unsigned short us[8]; bfrag b; } H, L;
    #pragma unroll
    for (int i = 0; i < 8; i++) {
        unsigned pr = split2p(v[i]);
        H.us[i] = (unsigned short)pr;
        L.us[i] = (unsigned short)(pr >> 16);
    }
    ah = H.b;
    al = L.b;
}

// ---------------- degree from RAW edges (per-block dtype sampling) ----------------
// int64 layout: 2E longlongs (src[E], dst[E]); int32: 2E ints. A block samples 64 odd
// words of its span: all-zero => int64 (int32 would need 16+ random node-ids == 0).
__global__ __launch_bounds__(256) void deg_raw(const unsigned* __restrict__ raw, int* __restrict__ deg,
                                               int* __restrict__ gmode, int E) {
    __shared__ int smode;
    int p0 = blockIdx.x * 1024;
    if (threadIdx.x < 64) {
        int p = p0 + threadIdx.x * 16;
        unsigned v = (p < E) ? raw[2 * p + 1] : 0u;
        unsigned long long any = __ballot(v != 0u);
        if (threadIdx.x == 0) smode = (any != 0ull) ? 1 : 0;
    }
    __syncthreads();
    int m = smode;
    if (blockIdx.x == 0 && threadIdx.x == 0) *gmode = m;   // all blocks agree
    int pend = min(p0 + 1024, E);
    for (int p = p0 + threadIdx.x; p < pend; p += 256) {
        int d = m ? (int)raw[E + p] : (int)((const unsigned long long*)raw)[E + p];
        atomicAdd(&deg[d], 1);
    }
}

// ---- contention-free degree-bucket ranking (counting sort, hierarchical) ----
// A: per-block LDS histogram + local rank; dinv
__global__ __launch_bounds__(256) void rank_block(const int* __restrict__ deg, float* __restrict__ dinv,
                                                  int* __restrict__ local_rank, int* __restrict__ hist_blk, int N) {
    __shared__ int h[256];
    int t = threadIdx.x;
    h[t] = 0;
    __syncthreads();
    int i = blockIdx.x * 256 + t;
    if (i < N) {
        int d = deg[i];
        dinv[i] = 1.0f / sqrtf((float)(d + 1));   // +1 self-loop
        int b = min(d, 255);
        local_rank[i] = atomicAdd(&h[b], 1);      // LDS atomic: intra-block only
    }
    __syncthreads();
    hist_blk[blockIdx.x * 256 + t] = h[t];
}

// B: thread b scans bin b across blocks (8-unrolled: 8 loads in flight),
//    then LDS dual-scan over bins -> binbase (count) and ebase (edges)
__global__ __launch_bounds__(256) void scan_blocks(int* __restrict__ hist_blk, int* __restrict__ binbase,
                                                   int* __restrict__ ebase, int nblk) {
    int b = threadIdx.x;
    int sum = 0;
    int k = 0;
    for (; k + 8 <= nblk; k += 8) {
        int v[8];
        #pragma unroll
        for (int u = 0; u < 8; u++) v[u] = hist_blk[(k + u) * 256 + b];
        #pragma unroll
        for (int u = 0; u < 8; u++) { hist_blk[(k + u) * 256 + b] = sum; sum += v[u]; }
    }
    for (; k < nblk; k++) {
        int v = hist_blk[k * 256 + b];
        hist_blk[k * 256 + b] = sum;
        sum += v;
    }
    __shared__ int s[256], s2[256];
    int c = sum, e = sum * b;
    s[b] = c; s2[b] = e;
    __syncthreads();
    for (int off = 1; off < 256; off <<= 1) {
        int a0 = (b >= off) ? s[b - off] : 0;
        int a1 = (b >= off) ? s2[b - off] : 0;
        __syncthreads();
        s[b] += a0; s2[b] += a1;
        __syncthreads();
    }
    binbase[b] = s[b] - c;
    ebase[b] = s2[b] - e;
}

// C: emit sorted meta + rowbeg (exact slot arithmetic, no contended atomics)
__global__ __launch_bounds__(256) void emit_perm(const int* __restrict__ deg, const float* __restrict__ dinv,
                                                 const int* __restrict__ local_rank, const int* __restrict__ hist_blk,
                                                 const int* __restrict__ binbase, const int* __restrict__ ebase,
                                                 int* __restrict__ tailcur, int* __restrict__ rowbeg,
                                                 int* __restrict__ cursor, uint4* __restrict__ meta, int N) {
    int i = blockIdx.x * 256 + threadIdx.x;
    if (i >= N) return;
    int d = deg[i];
    int b = min(d, 255);
    int rib = hist_blk[blockIdx.x * 256 + b] + local_rank[i];   // rank within bin
    int pos = binbase[b] + rib;
    int rb = (b < 255) ? (ebase[b] + rib * b) : (ebase[255] + atomicAdd(tailcur, d));
    rowbeg[i] = rb;
    cursor[i] = 0;
    meta[pos] = make_uint4((unsigned)rb, (unsigned)d, __float_as_uint(dinv[i]), (unsigned)i);
}

// ---------------- CSR fill from RAW edges; src fits ushort (N < 65536) ----------------
__global__ __launch_bounds__(256) void fill_csr_raw(const unsigned* __restrict__ raw, const int* __restrict__ gmode,
                                                    const int* __restrict__ rowbeg, int* __restrict__ cursor,
                                                    unsigned short* __restrict__ csr16, int E) {
    int e = blockIdx.x * 256 + threadIdx.x;
    if (e >= E) return;
    int m = *gmode;
    int d = m ? (int)raw[E + e] : (int)((const unsigned long long*)raw)[E + e];
    int s = m ? (int)raw[e]     : (int)((const unsigned long long*)raw)[e];
    int pos = atomicAdd(&cursor[d], 1);
    csr16[rowbeg[d] + pos] = (unsigned short)s;
}

// ---------------- all weights: transpose + split (4 matrices, one dispatch) ----------------
__global__ __launch_bounds__(256) void prep_w_all(const float* __restrict__ Wpre, const float* __restrict__ W1,
                                                  const float* __restrict__ W2, const float* __restrict__ Wpost,
                                                  unsigned short* __restrict__ preh, unsigned short* __restrict__ prel,
                                                  unsigned short* __restrict__ w1h, unsigned short* __restrict__ w1l,
                                                  unsigned short* __restrict__ w2h, unsigned short* __restrict__ w2l,
                                                  unsigned short* __restrict__ poh, unsigned short* __restrict__ pol) {
    int i = blockIdx.x * 256 + threadIdx.x;
    const float* W; unsigned short *wh, *wl; int idx, ncols;
    if (i < 16384)      { W = Wpre;  wh = preh; wl = prel; idx = i;         ncols = 128; }
    else if (i < 32768) { W = W1;    wh = w1h;  wl = w1l;  idx = i - 16384; ncols = 128; }
    else if (i < 49152) { W = W2;    wh = w2h;  wl = w2l;  idx = i - 32768; ncols = 128; }
    else if (i < 55296) { W = Wpost; wh = poh;  wl = pol;  idx = i - 49152; ncols = 40;  }
    else return;
    int n = idx >> 7, k = idx & 127;
    float v = (n < ncols) ? W[k * ncols + n] : 0.f;
    unsigned p = split2p(v);
    wh[idx] = (unsigned short)p;
    wl[idx] = (unsigned short)(p >> 16);
}

// ---------------- bf16x3 MFMA GEMM, software-pipelined, col-halves fused per block ----------------
// NW=8 (512 thr): wave w -> strip-slot w>>1, col-half (w&1)*64; both halves on SAME CU so the
// second wave's A loads hit L1 (A fetched from HBM once). NW=4 (256 thr): 4 slots, cols 0..NTILES*16.
// Next strip's A staged as raw uint4 BEFORE current strip's MFMA (latency hidden).
// AFMT=0: A is pair plane. AFMT=1: A is fp32 (split in-register).
// EPI=0: Cf fp32 CHUNKED t'[chunk][row][16] PRE-SCALED by dinv[row].
// EPI=1: bias -> pair plane Pout.  EPI=2: bias + fp32 flat, col<outW mask.
template<int NTILES, int EPI, int AFMT, int NW>
__global__ __launch_bounds__(NW * 64) void gemm_mfma(const void* __restrict__ Ap,
                                                     const unsigned short* __restrict__ Wth,
                                                     const unsigned short* __restrict__ Wtl,
                                                     const float* __restrict__ bias,
                                                     const float* __restrict__ dinv,
                                                     float* __restrict__ Cf,
                                                     uint32* __restrict__ Pout,
                                                     int nStrips, int N, int outW) {
    int wave = threadIdx.x >> 6;
    int lane = threadIdx.x & 63;
    int l15 = lane & 15, lg = lane >> 4;
    int so, colbase;
    if (NW == 8) { so = wave >> 1; colbase = (wave & 1) * 64; }
    else         { so = wave;      colbase = 0; }
    size_t chunkStride = (size_t)nStrips * 256;   // Npad*16 floats per 16-col chunk

    // persistent B fragments: wt[col][k] contiguous in k -> 16B per lane
    bfrag wh[4][NTILES], wl[4][NTILES];
    #pragma unroll
    for (int ks = 0; ks < 4; ks++)
        #pragma unroll
        for (int nt = 0; nt < NTILES; nt++) {
            size_t off = (size_t)(colbase + nt * 16 + l15) * D + ks * 32 + lg * 8;
            wh[ks][nt] = *(const bfrag*)(Wth + off);
            wl[ks][nt] = *(const bfrag*)(Wtl + off);
        }

    const int stride = gridDim.x * 4;
    int strip = blockIdx.x * 4 + so;
    if (strip >= nStrips) return;

    // raw A staging: 8x uint4 per strip (4 ks x 32B)
    uint4 cur[8];
    auto loadraw = [&](int s, uint4* r) {
        int arow = min(s * 16 + l15, N - 1);
        const uint4* p = (const uint4*)Ap + (size_t)arow * 32 + lg * 2;
        #pragma unroll
        for (int ks = 0; ks < 4; ks++) {
            r[2 * ks]     = p[ks * 8];
            r[2 * ks + 1] = p[ks * 8 + 1];
        }
    };

    loadraw(strip, cur);
    while (true) {
        int next = strip + stride;
        bool has_next = next < nStrips;
        uint4 nxt[8];
        if (has_next) loadraw(next, nxt);   // issue next loads before MFMA

        bfrag ah[4], al[4];
        #pragma unroll
        for (int ks = 0; ks < 4; ks++) {
            if (AFMT == 0) unpair_r(cur[2 * ks], cur[2 * ks + 1], ah[ks], al[ks]);
            else           split8_r(cur[2 * ks], cur[2 * ks + 1], ah[ks], al[ks]);
        }
        f32x4 acc[NTILES];
        #pragma unroll
        for (int nt = 0; nt < NTILES; nt++) acc[nt] = (f32x4){0.f, 0.f, 0.f, 0.f};
        #pragma unroll
        for (int ks = 0; ks < 4; ks++) {
            #pragma unroll
            for (int nt = 0; nt < NTILES; nt++)
                acc[nt] = __builtin_amdgcn_mfma_f32_16x16x32_bf16(ah[ks], wh[ks][nt], acc[nt], 0, 0, 0);
            #pragma unroll
            for (int nt = 0; nt < NTILES; nt++)
                acc[nt] = __builtin_amdgcn_mfma_f32_16x16x32_bf16(ah[ks], wl[ks][nt], acc[nt], 0, 0, 0);
            #pragma unroll
            for (int nt = 0; nt < NTILES; nt++)
                acc[nt] = __builtin_amdgcn_mfma_f32_16x16x32_bf16(al[ks], wh[ks][nt], acc[nt], 0, 0, 0);
        }

        int row0 = strip * 16;
        float dv[4];
        if (EPI == 0) {
            #pragma unroll
            for (int r = 0; r < 4; r++) {
                int row = row0 + lg * 4 + r;
                dv[r] = (row < N) ? dinv[row] : 0.f;
            }
        }
        // C/D layout (m89-verified): col = lane&15, row = (lane>>4)*4 + reg
        #pragma unroll
        for (int nt = 0; nt < NTILES; nt++) {
            int col = colbase + nt * 16 + l15;
            #pragma unroll
            for (int r = 0; r < 4; r++) {
                int row = row0 + lg * 4 + r;
                if (row >= N) continue;
                float v = acc[nt][r];
                if (EPI == 0) {
                    Cf[(size_t)(col >> 4) * chunkStride + (size_t)row * 16 + (col & 15)] = v * dv[r];
                } else if (EPI == 1) {
                    Pout[(size_t)row * D + col] = split2p(v + bias[col]);
                } else {
                    if (col < outW) Cf[(size_t)row * outW + col] = v + bias[col];
                }
            }
        }
        if (!has_next) break;
        #pragma unroll
        for (int i = 0; i < 8; i++) cur[i] = nxt[i];
        strip = next;
    }
}

// ---------------- XCD-pinned chunked gather, degree-sorted, 4-deep edge-way parallel ----------------
__global__ __launch_bounds__(256) void gather_xcd(const unsigned short* __restrict__ csr16,
                                                  const uint4* __restrict__ meta,
                                                  const float* __restrict__ t_c, const float* __restrict__ bias,
                                                  uint32* __restrict__ Pout, int N, int nStrips) {
    int chunk = blockIdx.x & 7;
    int k = (blockIdx.x >> 3) * 16 + (threadIdx.x >> 4);   // sorted position
    if (k >= N) return;
    uint4 m = meta[k];
    int beg = (int)m.x;
    int end = beg + (int)m.y;
    float di = __uint_as_float(m.z);
    int node = (int)m.w;
    int w = (threadIdx.x >> 2) & 3;
    int c = threadIdx.x & 3;
    const float* tc = t_c + (size_t)chunk * nStrips * 256 + c * 4;
    float4 a0 = make_float4(0.f, 0.f, 0.f, 0.f);
    float4 a1 = make_float4(0.f, 0.f, 0.f, 0.f);
    int j = beg + w;
    for (; j + 12 < end; j += 16) {
        int o0 = csr16[j];
        int o1 = csr16[j + 4];
        int o2 = csr16[j + 8];
        int o3 = csr16[j + 12];
        float4 v0 = *(const float4*)(tc + ((size_t)o0 << 4));
        float4 v1 = *(const float4*)(tc + ((size_t)o1 << 4));
        float4 v2 = *(const float4*)(tc + ((size_t)o2 << 4));
        float4 v3 = *(const float4*)(tc + ((size_t)o3 << 4));
        a0.x += v0.x; a0.y += v0.y; a0.z += v0.z; a0.w += v0.w;
        a1.x += v1.x; a1.y += v1.y; a1.z += v1.z; a1.w += v1.w;
        a0.x += v2.x; a0.y += v2.y; a0.z += v2.z; a0.w += v2.w;
        a1.x += v3.x; a1.y += v3.y; a1.z += v3.z; a1.w += v3.w;
    }
    for (; j < end; j += 4) {
        int o0 = csr16[j];
        float4 v0 = *(const float4*)(tc + ((size_t)o0 << 4));
        a0.x += v0.x; a0.y += v0.y; a0.z += v0.z; a0.w += v0.w;
    }
    a0.x += a1.x; a0.y += a1.y; a0.z += a1.z; a0.w += a1.w;
    // combine 4 edge-ways (lane bits 2-3)
    a0.x += __shfl_xor(a0.x, 4); a0.y += __shfl_xor(a0.y, 4);
    a0.z += __shfl_xor(a0.z, 4); a0.w += __shfl_xor(a0.w, 4);
    a0.x += __shfl_xor(a0.x, 8); a0.y += __shfl_xor(a0.y, 8);
    a0.z += __shfl_xor(a0.z, 8); a0.w += __shfl_xor(a0.w, 8);
    if (w != 0) return;
    // t' pre-scaled by dinv: out = dinv[d]*(sum + t'[d]) + b
    float4 tv = *(const float4*)(tc + (size_t)node * 16);
    int col0 = chunk * 16 + c * 4;
    float4 b = *((const float4*)bias + (col0 >> 2));
    float4 r;
    r.x = fmaxf(fmaf(di, a0.x + tv.x, b.x), 0.f);
    r.y = fmaxf(fmaf(di, a0.y + tv.y, b.y), 0.f);
    r.z = fmaxf(fmaf(di, a0.z + tv.z, b.z), 0.f);
    r.w = fmaxf(fmaf(di, a0.w + tv.w, b.w), 0.f);
    uint4 p;
    p.x = split2p(r.x); p.y = split2p(r.y); p.z = split2p(r.z); p.w = split2p(r.w);
    *(uint4*)(Pout + (size_t)node * D + col0) = p;
}

extern "C" void kernel_launch(void* const* d_in, const int* in_sizes, int n_in,
                              void* d_out, int out_size, void* d_ws, size_t ws_size,
                              hipStream_t stream) {
    const float* x      = (const float*)d_in[0];
    const unsigned* edges = (const unsigned*)d_in[1];
    const float* W_pre  = (const float*)d_in[2];
    const float* b_pre  = (const float*)d_in[3];
    const float* W1     = (const float*)d_in[4];
    const float* b1     = (const float*)d_in[5];
    const float* W2     = (const float*)d_in[6];
    const float* b2     = (const float*)d_in[7];
    const float* W_post = (const float*)d_in[8];
    const float* b_post = (const float*)d_in[9];
    float* out = (float*)d_out;

    const int N = in_sizes[0] / D;        // 50000
    const int E = in_sizes[1] / 2;        // 800000
    const int nStrips = (N + 15) / 16;    // 3125
    const int Npad = nStrips * 16;
    const int nBlk = (N + 255) / 256;     // 196

    // ---- workspace layout (persistent buffers) ----
    char* ws = (char*)d_ws;
    size_t off = 0;
    auto alloc = [&](size_t bytes) { void* p = ws + off; off += (bytes + 255) & ~(size_t)255; return p; };
    uint32* pairA = (uint32*)alloc((size_t)Npad * D * 4);   // pair plane A
    uint32* pairB = (uint32*)alloc((size_t)Npad * D * 4);   // pair plane B
    float*  bufT  = (float*)alloc((size_t)Npad * D * 4);    // chunked pre-scaled t'[8][Npad][16]
    float*  dinv    = (float*)alloc((size_t)N * 4);
    int*    deg     = (int*)alloc((size_t)N * 4);
    int*    rowbeg  = (int*)alloc((size_t)N * 4);
    unsigned short* csr16 = (unsigned short*)alloc((size_t)E * 2);
    uint4*  meta    = (uint4*)alloc((size_t)N * 16);
    unsigned short* wpre_h  = (unsigned short*)alloc(128 * 128 * 2);
    unsigned short* wpre_l  = (unsigned short*)alloc(128 * 128 * 2);
    unsigned short* w1_h    = (unsigned short*)alloc(128 * 128 * 2);
    unsigned short* w1_l    = (unsigned short*)alloc(128 * 128 * 2);
    unsigned short* w2_h    = (unsigned short*)alloc(128 * 128 * 2);
    unsigned short* w2_l    = (unsigned short*)alloc(128 * 128 * 2);
    unsigned short* wpost_h = (unsigned short*)alloc(48 * 128 * 2);
    unsigned short* wpost_l = (unsigned short*)alloc(48 * 128 * 2);

    // ---- prep-phase temporaries OVERLAY bufT (dead before first bufT write) ----
    {
        char* t = (char*)bufT;
        size_t toff = 0;
        auto talloc = [&](size_t bytes) { void* p = t + toff; toff += (bytes + 255) & ~(size_t)255; return p; };
        int* cursor     = (int*)talloc((size_t)N * 4);
        int* local_rank = (int*)talloc((size_t)N * 4);
        int* hist_blk   = (int*)talloc((size_t)nBlk * 256 * 4); // ~200 KB
        int* mode2      = (int*)talloc(256);                    // [0]=gmode, [1]=tail cursor
        int* binbase    = (int*)talloc(1024);
        int* ebase      = (int*)talloc(1024);
        int* gmode = mode2;
        int* tailcur = mode2 + 1;

        (void)hipMemsetAsync(mode2, 0, 8, stream);
        (void)hipMemsetAsync(deg, 0, (size_t)N * 4, stream);
        deg_raw<<<(E + 1023) / 1024, 256, 0, stream>>>(edges, deg, gmode, E);
        rank_block<<<nBlk, 256, 0, stream>>>(deg, dinv, local_rank, hist_blk, N);
        scan_blocks<<<1, 256, 0, stream>>>(hist_blk, binbase, ebase, nBlk);
        emit_perm<<<nBlk, 256, 0, stream>>>(deg, dinv, local_rank, hist_blk, binbase, ebase,
                                            tailcur, rowbeg, cursor, meta, N);
        fill_csr_raw<<<(E + 255) / 256, 256, 0, stream>>>(edges, gmode, rowbeg, cursor, csr16, E);
    }

    // weights: transpose + split, one dispatch
    prep_w_all<<<216, 256, 0, stream>>>(W_pre, W1, W2, W_post,
                                        wpre_h, wpre_l, w1_h, w1_l, w2_h, w2_l, wpost_h, wpost_l);

    const int nGatherBlocks = ((N + 15) / 16) * 8;   // 3125 node-blocks x 8 XCD chunks

    // pre MLP: h1(pairB) = x @ W_pre + b_pre  (x split in-register; 512-thr fused col-halves)
    gemm_mfma<4, 1, 1, 8><<<196, 512, 0, stream>>>(x, wpre_h, wpre_l, b_pre, nullptr, nullptr, pairB, nStrips, N, D);

    // conv1: t' = dinv*(h1 @ W1) (chunked) ; h2(pairA) = relu(dinv*(gather+self) + b1)
    gemm_mfma<4, 0, 0, 8><<<196, 512, 0, stream>>>(pairB, w1_h, w1_l, nullptr, dinv, bufT, nullptr, nStrips, N, D);
    gather_xcd<<<nGatherBlocks, 256, 0, stream>>>(csr16, meta, bufT, b1, pairA, N, nStrips);

    // conv2
    gemm_mfma<4, 0, 0, 8><<<196, 512, 0, stream>>>(pairA, w2_h, w2_l, nullptr, dinv, bufT, nullptr, nStrips, N, D);
    gather_xcd<<<nGatherBlocks, 256, 0, stream>>>(csr16, meta, bufT, b2, pairB, N, nStrips);

    // post MLP: out = h3 @ W_post + b_post  (40 cols, padded to 48)
    gemm_mfma<3, 2, 0, 4><<<196, 256, 0, stream>>>(pairB, wpost_h, wpost_l, b_post, nullptr, out, nullptr, nStrips, N, 40);
}